// Round 1
// baseline (609.618 us; speedup 1.0000x reference)
//
#include <hip/hip_runtime.h>
#include <hip/hip_bf16.h>

// Problem constants (fixed by the reference)
#define NB 4
#define NQ 32768
#define NC 64
#define NHH 256
#define NWW 256
#define NHW 65536
#define NTOK (NB * NQ)

__device__ __forceinline__ float wsum64(float v) {
    #pragma unroll
    for (int m = 1; m < 64; m <<= 1) v += __shfl_xor(v, m, 64);
    return v;
}

__device__ __forceinline__ float gsum8(float v) {
    v += __shfl_xor(v, 1, 64);
    v += __shfl_xor(v, 2, 64);
    v += __shfl_xor(v, 4, 64);
    return v;
}

// jax.nn.gelu default: approximate=True (tanh form)
__device__ __forceinline__ float gelu_tanh(float u) {
    float z = 0.7978845608028654f * (u + 0.044715f * u * u * u);
    float e = __expf(2.0f * z);
    return u - u / (e + 1.0f);   // == 0.5*u*(1+tanh(z)), NaN/overflow-safe
}

// (B,C,H,W) -> (B,H*W,C) so token gathers become one contiguous 256B read.
__global__ __launch_bounds__(256) void feat_transpose_kernel(
        const float* __restrict__ feat, float* __restrict__ featT) {
    __shared__ float tile[64][65];
    int blk = blockIdx.x;          // NB * (NHW/64) = 4096 blocks
    int b = blk >> 10;             // 1024 tiles per batch
    int hw0 = (blk & 1023) << 6;
    int lane = threadIdx.x & 63;
    int row = threadIdx.x >> 6;    // 0..3
    const float* src = feat + ((size_t)b * NC) * NHW + hw0;
    #pragma unroll
    for (int cc = 0; cc < 16; ++cc) {
        int c = (cc << 2) + row;
        tile[c][lane] = src[(size_t)c * NHW + lane];   // coalesced 256B
    }
    __syncthreads();
    float* dst = featT + ((size_t)b * NHW + hw0) * NC;
    #pragma unroll
    for (int ww = 0; ww < 16; ++ww) {
        int w = (ww << 2) + row;
        dst[(size_t)w * NC + lane] = tile[lane][w];    // coalesced 256B, pad-65 avoids conflicts
    }
}

// One wave (64 lanes) per token; lane == channel.
template<bool USE_T>
__global__ __launch_bounds__(256) void token_kernel(
    const float* __restrict__ depth, const float* __restrict__ feat,
    const float* __restrict__ featT, const float* __restrict__ coord,
    const float* __restrict__ w_ce, const float* __restrict__ b_ce,
    const float* __restrict__ ln1_g, const float* __restrict__ ln1_b,
    const float* __restrict__ w_q, const float* __restrict__ w_k,
    const float* __restrict__ w_v, const float* __restrict__ w_o,
    const float* __restrict__ b_o, const float* __restrict__ ln2_g,
    const float* __restrict__ ln2_b, const float* __restrict__ w_m1,
    const float* __restrict__ b_m1, const float* __restrict__ w_m2,
    const float* __restrict__ b_m2, const float* __restrict__ w_head,
    float* __restrict__ out)
{
    __shared__ float lds[4][256];        // per-wave staging region (disjoint)
    const int wid = threadIdx.x >> 6;
    const int lane = threadIdx.x & 63;
    const int n = (blockIdx.x << 2) + wid;     // token id, grid = NTOK/4
    const int b = n >> 15;                     // Q = 32768
    float4* hb = (float4*)(&lds[wid][0]);      // [c][t] layout, float4 per c

    const float cy0 = coord[2 * n], cx0 = coord[2 * n + 1];
    const float r = 0.00390625f;               // 1/256
    const float wce0 = w_ce[lane], wce1 = w_ce[64 + lane], bce = b_ce[lane];

    float x[4], pred[4];
    // t order: (vx,vy) = (-1,-1),(-1,+1),(+1,-1),(+1,+1); vx shifts axis0(y), vy axis1(x)
    #pragma unroll
    for (int t = 0; t < 4; ++t) {
        float vx = (t < 2) ? -1.0f : 1.0f;
        float vy = (t & 1) ? 1.0f : -1.0f;
        float cy = cy0 + vx * r + 1e-6f;
        float cx = cx0 + vy * r + 1e-6f;
        cy = fminf(fmaxf(cy, -1.0f + 1e-6f), 1.0f - 1e-6f);
        cx = fminf(fmaxf(cx, -1.0f + 1e-6f), 1.0f - 1e-6f);
        int iy = (int)rintf((cy + 1.0f) * 128.0f - 0.5f);   // rintf = round-half-even (matches jnp.round)
        int ix = (int)rintf((cx + 1.0f) * 128.0f - 0.5f);
        iy = min(max(iy, 0), 255);
        ix = min(max(ix, 0), 255);
        int lin = iy * NWW + ix;
        pred[t] = depth[b * NHW + lin];                     // uniform broadcast load
        float tok = USE_T ? featT[((b * NHW + lin) << 6) + lane]
                          : feat[(((b << 6) + lane) << 16) + lin];
        // cell centers: ys[i] = -255/256 + i/128 (exact in f32)
        float ysy = -0.99609375f + 0.0078125f * (float)iy;
        float xsx = -0.99609375f + 0.0078125f * (float)ix;
        float rel0 = (cy0 - ysy) * 256.0f;                  // uses ORIGINAL coord
        float rel1 = (cx0 - xsx) * 256.0f;
        x[t] = tok + rel0 * wce0 + rel1 * wce1 + bce;       // x = tok + rel @ w_ce + b_ce
    }

    // ---- LN1 ----
    float h[4];
    {
        float g = ln1_g[lane], bb = ln1_b[lane];
        #pragma unroll
        for (int t = 0; t < 4; ++t) {
            float m = wsum64(x[t]) * 0.015625f;
            float s2 = wsum64(x[t] * x[t]) * 0.015625f;
            float var = s2 - m * m;
            h[t] = (x[t] - m) * rsqrtf(var + 1e-5f) * g + bb;
        }
    }

    // ---- QKV: q[t][lane] = sum_c h[t][c] * w[c][lane] via LDS broadcast ----
    __syncthreads();
    hb[lane] = make_float4(h[0], h[1], h[2], h[3]);
    __syncthreads();
    float qv[4] = {0, 0, 0, 0}, kv[4] = {0, 0, 0, 0}, vv[4] = {0, 0, 0, 0};
    #pragma unroll 8
    for (int c = 0; c < 64; ++c) {
        float4 hv = hb[c];                 // uniform address -> broadcast
        float a  = w_q[(c << 6) + lane];   // coalesced, L1-resident
        float bq = w_k[(c << 6) + lane];
        float cq = w_v[(c << 6) + lane];
        qv[0] += hv.x * a;  qv[1] += hv.y * a;  qv[2] += hv.z * a;  qv[3] += hv.w * a;
        kv[0] += hv.x * bq; kv[1] += hv.y * bq; kv[2] += hv.z * bq; kv[3] += hv.w * bq;
        vv[0] += hv.x * cq; vv[1] += hv.y * cq; vv[2] += hv.z * cq; vv[3] += hv.w * cq;
    }

    // ---- attention: heads = 8-lane groups (head = lane>>3, d = lane&7) ----
    float att[4][4];
    #pragma unroll
    for (int t = 0; t < 4; ++t) {
        #pragma unroll
        for (int s = 0; s < 4; ++s)
            att[t][s] = gsum8(qv[t] * kv[s]) * 0.3535533905932738f;  // 1/sqrt(8)
    }
    float o[4];
    #pragma unroll
    for (int t = 0; t < 4; ++t) {
        float m = fmaxf(fmaxf(att[t][0], att[t][1]), fmaxf(att[t][2], att[t][3]));
        float e0 = __expf(att[t][0] - m), e1 = __expf(att[t][1] - m);
        float e2 = __expf(att[t][2] - m), e3 = __expf(att[t][3] - m);
        float inv = 1.0f / (e0 + e1 + e2 + e3);
        o[t] = (e0 * vv[0] + e1 * vv[1] + e2 * vv[2] + e3 * vv[3]) * inv;
    }

    // ---- o @ w_o + residual ----
    __syncthreads();
    hb[lane] = make_float4(o[0], o[1], o[2], o[3]);
    __syncthreads();
    {
        float acc[4] = {0, 0, 0, 0};
        #pragma unroll 8
        for (int c = 0; c < 64; ++c) {
            float4 hv = hb[c];
            float a = w_o[(c << 6) + lane];
            acc[0] += hv.x * a; acc[1] += hv.y * a; acc[2] += hv.z * a; acc[3] += hv.w * a;
        }
        float bo = b_o[lane];
        #pragma unroll
        for (int t = 0; t < 4; ++t) x[t] += acc[t] + bo;
    }

    // ---- LN2 ----
    float h2[4];
    {
        float g = ln2_g[lane], bb = ln2_b[lane];
        #pragma unroll
        for (int t = 0; t < 4; ++t) {
            float m = wsum64(x[t]) * 0.015625f;
            float s2 = wsum64(x[t] * x[t]) * 0.015625f;
            float var = s2 - m * m;
            h2[t] = (x[t] - m) * rsqrtf(var + 1e-5f) * g + bb;
        }
    }

    // ---- MLP: gelu(h2 @ w_m1 + b_m1) @ w_m2 + b_m2, residual ----
    __syncthreads();
    hb[lane] = make_float4(h2[0], h2[1], h2[2], h2[3]);
    __syncthreads();
    float gl[4];
    {
        float acc[4] = {0, 0, 0, 0};
        #pragma unroll 8
        for (int c = 0; c < 64; ++c) {
            float4 hv = hb[c];
            float a = w_m1[(c << 6) + lane];
            acc[0] += hv.x * a; acc[1] += hv.y * a; acc[2] += hv.z * a; acc[3] += hv.w * a;
        }
        float bm = b_m1[lane];
        #pragma unroll
        for (int t = 0; t < 4; ++t) gl[t] = gelu_tanh(acc[t] + bm);
    }
    __syncthreads();
    hb[lane] = make_float4(gl[0], gl[1], gl[2], gl[3]);
    __syncthreads();
    {
        float acc[4] = {0, 0, 0, 0};
        #pragma unroll 8
        for (int c = 0; c < 64; ++c) {
            float4 hv = hb[c];
            float a = w_m2[(c << 6) + lane];
            acc[0] += hv.x * a; acc[1] += hv.y * a; acc[2] += hv.z * a; acc[3] += hv.w * a;
        }
        float bm = b_m2[lane];
        #pragma unroll
        for (int t = 0; t < 4; ++t) x[t] += acc[t] + bm;
    }

    // ---- head: softmax(x @ w_head) over t; b_head cancels in softmax ----
    float wh = w_head[lane];
    float lg0 = wsum64(x[0] * wh);
    float lg1 = wsum64(x[1] * wh);
    float lg2 = wsum64(x[2] * wh);
    float lg3 = wsum64(x[3] * wh);
    float m = fmaxf(fmaxf(lg0, lg1), fmaxf(lg2, lg3));
    float e0 = __expf(lg0 - m), e1 = __expf(lg1 - m);
    float e2 = __expf(lg2 - m), e3 = __expf(lg3 - m);
    float res = (pred[0] * e0 + pred[1] * e1 + pred[2] * e2 + pred[3] * e3)
              / (e0 + e1 + e2 + e3);
    if (lane == 0) out[n] = res;
}

extern "C" void kernel_launch(void* const* d_in, const int* in_sizes, int n_in,
                              void* d_out, int out_size, void* d_ws, size_t ws_size,
                              hipStream_t stream) {
    const float* depth  = (const float*)d_in[0];
    const float* feat   = (const float*)d_in[1];
    const float* coord  = (const float*)d_in[2];
    const float* w_ce   = (const float*)d_in[3];
    const float* b_ce   = (const float*)d_in[4];
    const float* ln1_g  = (const float*)d_in[5];
    const float* ln1_b  = (const float*)d_in[6];
    const float* w_q    = (const float*)d_in[7];
    const float* w_k    = (const float*)d_in[8];
    const float* w_v    = (const float*)d_in[9];
    const float* w_o    = (const float*)d_in[10];
    const float* b_o    = (const float*)d_in[11];
    const float* ln2_g  = (const float*)d_in[12];
    const float* ln2_b  = (const float*)d_in[13];
    const float* w_m1   = (const float*)d_in[14];
    const float* b_m1   = (const float*)d_in[15];
    const float* w_m2   = (const float*)d_in[16];
    const float* b_m2   = (const float*)d_in[17];
    const float* w_head = (const float*)d_in[18];
    float* outp = (float*)d_out;

    const size_t featT_bytes = (size_t)NB * NHW * NC * sizeof(float);
    float* featT = (float*)d_ws;
    bool use_t = (d_ws != nullptr) && (ws_size >= featT_bytes);

    if (use_t) {
        feat_transpose_kernel<<<NB * (NHW / 64), 256, 0, stream>>>(feat, featT);
        token_kernel<true><<<NTOK / 4, 256, 0, stream>>>(
            depth, feat, featT, coord, w_ce, b_ce, ln1_g, ln1_b,
            w_q, w_k, w_v, w_o, b_o, ln2_g, ln2_b,
            w_m1, b_m1, w_m2, b_m2, w_head, outp);
    } else {
        token_kernel<false><<<NTOK / 4, 256, 0, stream>>>(
            depth, feat, featT, coord, w_ce, b_ce, ln1_g, ln1_b,
            w_q, w_k, w_v, w_o, b_o, ln2_g, ln2_b,
            w_m1, b_m1, w_m2, b_m2, w_head, outp);
    }
}

// Round 2
// 181.867 us; speedup vs baseline: 3.3520x; 3.3520x over previous
//
#include <hip/hip_runtime.h>
#include <hip/hip_bf16.h>

#define NB 4
#define NQ 32768
#define NHW 65536
#define NTOK (NB * NQ)

typedef __attribute__((ext_vector_type(8))) short short8;   // 8 bf16 = 4 VGPR (MFMA A/B frag)
typedef __attribute__((ext_vector_type(4))) float f32x4;    // MFMA C/D frag

__device__ __forceinline__ unsigned short f2bf(float f) {
    unsigned int u = __float_as_uint(f);
    u = (u + 0x7FFFu + ((u >> 16) & 1u)) >> 16;   // RNE
    return (unsigned short)u;
}

__device__ __forceinline__ float gelu_tanh(float u) {
    float z = 0.7978845608028654f * (u + 0.044715f * u * u * u);
    float e = __expf(2.0f * z);
    return u - u / (e + 1.0f);   // 0.5*u*(1+tanh(z)), overflow-safe
}

// (B,C,H,W) -> (B,H*W,C)
__global__ __launch_bounds__(256) void feat_transpose_kernel(
        const float* __restrict__ feat, float* __restrict__ featT) {
    __shared__ float tile[64][65];
    int blk = blockIdx.x;
    int b = blk >> 10;
    int hw0 = (blk & 1023) << 6;
    int lane = threadIdx.x & 63;
    int row = threadIdx.x >> 6;
    const float* src = feat + ((size_t)b * 64) * NHW + hw0;
    #pragma unroll
    for (int cc = 0; cc < 16; ++cc) {
        int c = (cc << 2) + row;
        tile[c][lane] = src[(size_t)c * NHW + lane];
    }
    __syncthreads();
    float* dst = featT + ((size_t)b * NHW + hw0) * 64;
    #pragma unroll
    for (int ww = 0; ww < 16; ++ww) {
        int w = (ww << 2) + row;
        dst[(size_t)w * 64 + lane] = tile[lane][w];
    }
}

// Pack 6 weight matrices (64x64 f32 row-major [k][n]) into bf16 B-fragment order:
// out[((mat*8 + kt*4+nt)*64 + lane)*8 + j] = W[8*(lane>>4)+j+32*kt][(lane&15)+16*nt]
__global__ __launch_bounds__(64) void wprep_kernel(
        const float* __restrict__ wq, const float* __restrict__ wk,
        const float* __restrict__ wv, const float* __restrict__ wo,
        const float* __restrict__ wm1, const float* __restrict__ wm2,
        unsigned short* __restrict__ out) {
    int bid = blockIdx.x;               // 48
    int mat = bid >> 3, ti = bid & 7;
    int kt = ti >> 2, nt = ti & 3;
    int l = threadIdx.x;
    const float* W = (mat == 0) ? wq : (mat == 1) ? wk : (mat == 2) ? wv
                   : (mat == 3) ? wo : (mat == 4) ? wm1 : wm2;
    unsigned short* dst = out + ((size_t)(bid) * 64 + l) * 8;
    #pragma unroll
    for (int j = 0; j < 8; ++j) {
        int k = 8 * (l >> 4) + j + 32 * kt;
        int n = (l & 15) + 16 * nt;
        dst[j] = f2bf(W[k * 64 + n]);
    }
}

// One wave = 4 tokens (M=16 rows). Lane holds rows 4g+i (g=lane>>4), chans (lane&15)+16j.
template<bool USE_T>
__global__ __launch_bounds__(256) void token_kernel(
    const float* __restrict__ depth, const float* __restrict__ feat,
    const float* __restrict__ featT, const float* __restrict__ coord,
    const float* __restrict__ w_ce, const float* __restrict__ b_ce,
    const float* __restrict__ ln1_g, const float* __restrict__ ln1_b,
    const float* __restrict__ b_o, const float* __restrict__ ln2_g,
    const float* __restrict__ ln2_b, const float* __restrict__ b_m1,
    const float* __restrict__ b_m2, const float* __restrict__ w_head,
    const unsigned short* __restrict__ wprep, float* __restrict__ out)
{
    __shared__ unsigned short alds[4][1024];   // 2KB per wave, [row 0..15][chan 0..63] bf16, XOR-swizzled
    const int wid = threadIdx.x >> 6;
    const int lane = threadIdx.x & 63;
    const int g = lane >> 4;       // token within wave
    const int li = lane & 15;
    const int n = ((blockIdx.x << 2) + wid) * 4 + g;
    const int b = n >> 15;
    char* mb = (char*)&alds[wid][0];

    // ---- gather + rel-coord embedding ----
    float x[4][4], pred[4];
    const float cy0 = coord[2 * n], cx0 = coord[2 * n + 1];
    #pragma unroll
    for (int i = 0; i < 4; ++i) {
        float vx = (i < 2) ? -1.0f : 1.0f;
        float vy = (i & 1) ? 1.0f : -1.0f;
        float cy = fminf(fmaxf(cy0 + vx * 0.00390625f + 1e-6f, -1.0f + 1e-6f), 1.0f - 1e-6f);
        float cx = fminf(fmaxf(cx0 + vy * 0.00390625f + 1e-6f, -1.0f + 1e-6f), 1.0f - 1e-6f);
        int iy = min(max((int)rintf((cy + 1.0f) * 128.0f - 0.5f), 0), 255);
        int ix = min(max((int)rintf((cx + 1.0f) * 128.0f - 0.5f), 0), 255);
        int lin = iy * 256 + ix;
        pred[i] = depth[(b << 16) + lin];
        float ysy = -0.99609375f + 0.0078125f * (float)iy;
        float xsx = -0.99609375f + 0.0078125f * (float)ix;
        float rel0 = (cy0 - ysy) * 256.0f;
        float rel1 = (cx0 - xsx) * 256.0f;
        #pragma unroll
        for (int j = 0; j < 4; ++j) {
            int c = li + 16 * j;
            float tok = USE_T ? featT[((size_t)((b << 16) + lin) << 6) + c]
                              : feat[(((size_t)(b * 64 + c)) << 16) + lin];
            x[i][j] = tok + rel0 * w_ce[c] + rel1 * w_ce[64 + c] + b_ce[c];
        }
    }

    // ---- helpers ----
    auto lnorm = [&](float xv[4][4], float hv[4][4],
                     const float* __restrict__ gp, const float* __restrict__ bp) {
        float gj[4], bj[4];
        #pragma unroll
        for (int j = 0; j < 4; ++j) { gj[j] = gp[li + 16 * j]; bj[j] = bp[li + 16 * j]; }
        #pragma unroll
        for (int i = 0; i < 4; ++i) {
            float s = xv[i][0] + xv[i][1] + xv[i][2] + xv[i][3];
            float ss = xv[i][0] * xv[i][0] + xv[i][1] * xv[i][1]
                     + xv[i][2] * xv[i][2] + xv[i][3] * xv[i][3];
            #pragma unroll
            for (int m = 1; m < 16; m <<= 1) {
                s += __shfl_xor(s, m, 64);
                ss += __shfl_xor(ss, m, 64);
            }
            float mean = s * 0.015625f;
            float var = ss * 0.015625f - mean * mean;
            float rs = rsqrtf(var + 1e-5f);
            #pragma unroll
            for (int j = 0; j < 4; ++j)
                hv[i][j] = (xv[i][j] - mean) * rs * gj[j] + bj[j];
        }
    };

    // write v (D-layout) into LDS as bf16 and read back the two A-fragments
    auto put_frag = [&](float v[4][4], short8& a0, short8& a1) {
        #pragma unroll
        for (int i = 0; i < 4; ++i) {
            int r = 4 * g + i;
            #pragma unroll
            for (int j = 0; j < 4; ++j) {
                int c = li + 16 * j;
                *(unsigned short*)(mb + 128 * r + 16 * ((c >> 3) ^ (r & 7)) + 2 * (c & 7))
                    = f2bf(v[i][j]);
            }
        }
        asm volatile("s_waitcnt lgkmcnt(0)" ::: "memory");
        a0 = *(const short8*)(mb + 128 * li + 16 * ((g) ^ (li & 7)));
        a1 = *(const short8*)(mb + 128 * li + 16 * ((4 + g) ^ (li & 7)));
    };

    auto gemm = [&](short8 a0, short8 a1, const short8* __restrict__ Wf, f32x4 acc[4]) {
        #pragma unroll
        for (int nt = 0; nt < 4; ++nt) {
            acc[nt] = __builtin_amdgcn_mfma_f32_16x16x32_bf16(a0, Wf[nt * 64 + lane], acc[nt], 0, 0, 0);
            acc[nt] = __builtin_amdgcn_mfma_f32_16x16x32_bf16(a1, Wf[(4 + nt) * 64 + lane], acc[nt], 0, 0, 0);
        }
    };

    const short8* Wq  = (const short8*)(wprep);
    const short8* Wk  = (const short8*)(wprep + 1 * 4096);
    const short8* Wv  = (const short8*)(wprep + 2 * 4096);
    const short8* Wo  = (const short8*)(wprep + 3 * 4096);
    const short8* Wm1 = (const short8*)(wprep + 4 * 4096);
    const short8* Wm2 = (const short8*)(wprep + 5 * 4096);
    const f32x4 z4 = {0.0f, 0.0f, 0.0f, 0.0f};

    // ---- LN1 + QKV ----
    float h[4][4];
    lnorm(x, h, ln1_g, ln1_b);
    short8 a0, a1;
    put_frag(h, a0, a1);
    f32x4 qa[4], ka[4], va[4];
    #pragma unroll
    for (int t = 0; t < 4; ++t) { qa[t] = z4; ka[t] = z4; va[t] = z4; }
    gemm(a0, a1, Wq, qa);
    gemm(a0, a1, Wk, ka);
    gemm(a0, a1, Wv, va);

    // ---- attention: head = chan>>3; d = 8-lane subgroup (lane&7) ----
    float o2[4][4];   // [i=t][j]
    #pragma unroll
    for (int j = 0; j < 4; ++j) {
        float at[4][4];
        #pragma unroll
        for (int t = 0; t < 4; ++t)
            #pragma unroll
            for (int s = 0; s < 4; ++s) {
                float p = qa[j][t] * ka[j][s];
                p += __shfl_xor(p, 1, 64);
                p += __shfl_xor(p, 2, 64);
                p += __shfl_xor(p, 4, 64);
                at[t][s] = p * 0.35355339059327378f;   // 1/sqrt(8)
            }
        #pragma unroll
        for (int t = 0; t < 4; ++t) {
            float m = fmaxf(fmaxf(at[t][0], at[t][1]), fmaxf(at[t][2], at[t][3]));
            float e0 = __expf(at[t][0] - m), e1 = __expf(at[t][1] - m);
            float e2 = __expf(at[t][2] - m), e3 = __expf(at[t][3] - m);
            float inv = 1.0f / (e0 + e1 + e2 + e3);
            o2[t][j] = (e0 * va[j][0] + e1 * va[j][1] + e2 * va[j][2] + e3 * va[j][3]) * inv;
        }
    }

    // ---- o @ w_o + b_o + residual ----
    put_frag(o2, a0, a1);
    f32x4 oa[4];
    #pragma unroll
    for (int t = 0; t < 4; ++t) oa[t] = z4;
    gemm(a0, a1, Wo, oa);
    {
        float bo[4];
        #pragma unroll
        for (int j = 0; j < 4; ++j) bo[j] = b_o[li + 16 * j];
        #pragma unroll
        for (int i = 0; i < 4; ++i)
            #pragma unroll
            for (int j = 0; j < 4; ++j) x[i][j] += oa[j][i] + bo[j];
    }

    // ---- LN2 + MLP ----
    float h2[4][4];
    lnorm(x, h2, ln2_g, ln2_b);
    put_frag(h2, a0, a1);
    f32x4 ma[4];
    #pragma unroll
    for (int t = 0; t < 4; ++t) ma[t] = z4;
    gemm(a0, a1, Wm1, ma);
    float g1[4][4];
    {
        float bm[4];
        #pragma unroll
        for (int j = 0; j < 4; ++j) bm[j] = b_m1[li + 16 * j];
        #pragma unroll
        for (int i = 0; i < 4; ++i)
            #pragma unroll
            for (int j = 0; j < 4; ++j) g1[i][j] = gelu_tanh(ma[j][i] + bm[j]);
    }
    put_frag(g1, a0, a1);
    f32x4 m2a[4];
    #pragma unroll
    for (int t = 0; t < 4; ++t) m2a[t] = z4;
    gemm(a0, a1, Wm2, m2a);
    {
        float bm[4];
        #pragma unroll
        for (int j = 0; j < 4; ++j) bm[j] = b_m2[li + 16 * j];
        #pragma unroll
        for (int i = 0; i < 4; ++i)
            #pragma unroll
            for (int j = 0; j < 4; ++j) x[i][j] += m2a[j][i] + bm[j];
    }

    // ---- head softmax over the 4 positions; weighted depth blend ----
    float wh[4];
    #pragma unroll
    for (int j = 0; j < 4; ++j) wh[j] = w_head[li + 16 * j];
    float lg[4];
    #pragma unroll
    for (int i = 0; i < 4; ++i) {
        float s = x[i][0] * wh[0] + x[i][1] * wh[1] + x[i][2] * wh[2] + x[i][3] * wh[3];
        #pragma unroll
        for (int m = 1; m < 16; m <<= 1) s += __shfl_xor(s, m, 64);
        lg[i] = s;
    }
    float m = fmaxf(fmaxf(lg[0], lg[1]), fmaxf(lg[2], lg[3]));
    float e0 = __expf(lg[0] - m), e1 = __expf(lg[1] - m);
    float e2 = __expf(lg[2] - m), e3 = __expf(lg[3] - m);
    float res = (pred[0] * e0 + pred[1] * e1 + pred[2] * e2 + pred[3] * e3)
              / (e0 + e1 + e2 + e3);
    if (li == 0) out[n] = res;
}

extern "C" void kernel_launch(void* const* d_in, const int* in_sizes, int n_in,
                              void* d_out, int out_size, void* d_ws, size_t ws_size,
                              hipStream_t stream) {
    const float* depth  = (const float*)d_in[0];
    const float* feat   = (const float*)d_in[1];
    const float* coord  = (const float*)d_in[2];
    const float* w_ce   = (const float*)d_in[3];
    const float* b_ce   = (const float*)d_in[4];
    const float* ln1_g  = (const float*)d_in[5];
    const float* ln1_b  = (const float*)d_in[6];
    const float* w_q    = (const float*)d_in[7];
    const float* w_k    = (const float*)d_in[8];
    const float* w_v    = (const float*)d_in[9];
    const float* w_o    = (const float*)d_in[10];
    const float* b_o    = (const float*)d_in[11];
    const float* ln2_g  = (const float*)d_in[12];
    const float* ln2_b  = (const float*)d_in[13];
    const float* w_m1   = (const float*)d_in[14];
    const float* b_m1   = (const float*)d_in[15];
    const float* w_m2   = (const float*)d_in[16];
    const float* b_m2   = (const float*)d_in[17];
    const float* w_head = (const float*)d_in[18];
    float* outp = (float*)d_out;

    unsigned short* wprep = (unsigned short*)d_ws;
    const size_t FEATT_OFF = 65536;                              // wprep uses 49152 B
    const size_t featT_bytes = (size_t)NB * NHW * 64 * sizeof(float);
    float* featT = (float*)((char*)d_ws + FEATT_OFF);
    bool use_t = (d_ws != nullptr) && (ws_size >= FEATT_OFF + featT_bytes);

    wprep_kernel<<<48, 64, 0, stream>>>(w_q, w_k, w_v, w_o, w_m1, w_m2, wprep);
    if (use_t) {
        feat_transpose_kernel<<<NB * (NHW / 64), 256, 0, stream>>>(feat, featT);
        token_kernel<true><<<NTOK / 16, 256, 0, stream>>>(
            depth, feat, featT, coord, w_ce, b_ce, ln1_g, ln1_b,
            b_o, ln2_g, ln2_b, b_m1, b_m2, w_head, wprep, outp);
    } else {
        token_kernel<false><<<NTOK / 16, 256, 0, stream>>>(
            depth, feat, featT, coord, w_ce, b_ce, ln1_g, ln1_b,
            b_o, ln2_g, ln2_b, b_m1, b_m2, w_head, wprep, outp);
    }
}

// Round 3
// 159.810 us; speedup vs baseline: 3.8146x; 1.1380x over previous
//
#include <hip/hip_runtime.h>
#include <hip/hip_bf16.h>

#define NB 4
#define NQ 32768
#define NHW 65536
#define NTOK (NB * NQ)

typedef __attribute__((ext_vector_type(8))) short short8;   // 8 bf16 = 4 VGPR (MFMA A/B frag)
typedef __attribute__((ext_vector_type(4))) float f32x4;    // MFMA C/D frag

__device__ __forceinline__ unsigned short f2bf(float f) {
    unsigned int u = __float_as_uint(f);
    u = (u + 0x7FFFu + ((u >> 16) & 1u)) >> 16;   // RNE (host-side prep only path)
    return (unsigned short)u;
}

__device__ __forceinline__ float gelu_tanh(float u) {
    float z = 0.7978845608028654f * (u + 0.044715f * u * u * u);
    float e = __expf(2.0f * z);
    return u - u / (e + 1.0f);   // 0.5*u*(1+tanh(z)), overflow-safe
}

// (B,C,H,W) f32 -> (B,H*W,64) bf16, channel-permuted: position p = (c&15)*4 + (c>>4)
// so a lane's 4 chans {li, li+16, li+32, li+48} are the 4 consecutive bf16 at p=4*li.
__global__ __launch_bounds__(256) void feat_transpose_kernel(
        const float* __restrict__ feat, unsigned int* __restrict__ featT) {
    __shared__ float tile[64][65];
    int blk = blockIdx.x;
    int b = blk >> 10;
    int hw0 = (blk & 1023) << 6;
    int lane = threadIdx.x & 63;
    int row = threadIdx.x >> 6;
    const float* src = feat + ((size_t)b * 64) * NHW + hw0;
    #pragma unroll
    for (int cc = 0; cc < 16; ++cc) {
        int c = (cc << 2) + row;
        tile[c][lane] = src[(size_t)c * NHW + lane];
    }
    __syncthreads();
    unsigned int* dst = featT + ((size_t)(b * NHW + hw0)) * 32;
    #pragma unroll
    for (int it = 0; it < 8; ++it) {
        int flat = it * 256 + threadIdx.x;
        int w = flat >> 5, pp = flat & 31;        // u32 pp covers positions 2pp,2pp+1
        int c1 = (pp >> 1) + 32 * (pp & 1);       // chan of lo; hi is c1+16
        unsigned int u;
        asm("v_cvt_pk_bf16_f32 %0, %1, %2" : "=v"(u) : "v"(tile[c1][w]), "v"(tile[c1 + 16][w]));
        dst[(size_t)w * 32 + pp] = u;
    }
}

// Pack 6 weight matrices (64x64 f32 [k][n]) into bf16 B-fragment order (as R2).
__global__ __launch_bounds__(64) void wprep_kernel(
        const float* __restrict__ wq, const float* __restrict__ wk,
        const float* __restrict__ wv, const float* __restrict__ wo,
        const float* __restrict__ wm1, const float* __restrict__ wm2,
        unsigned short* __restrict__ out) {
    int bid = blockIdx.x;               // 48
    int mat = bid >> 3, ti = bid & 7;
    int kt = ti >> 2, nt = ti & 3;
    int l = threadIdx.x;
    const float* W = (mat == 0) ? wq : (mat == 1) ? wk : (mat == 2) ? wv
                   : (mat == 3) ? wo : (mat == 4) ? wm1 : wm2;
    unsigned short* dst = out + ((size_t)(bid) * 64 + l) * 8;
    #pragma unroll
    for (int j = 0; j < 8; ++j) {
        int k = 8 * (l >> 4) + j + 32 * kt;
        int n = (l & 15) + 16 * nt;
        dst[j] = f2bf(W[k * 64 + n]);
    }
}

// One wave = 4 tokens (M=16 rows). Lane = (g = lane>>4 token, li = lane&15).
// D-layout: lane holds rows 4g+i, chans li+16*nt.
template<bool USE_T>
__global__ __launch_bounds__(256) void token_kernel(
    const float* __restrict__ depth, const float* __restrict__ feat,
    const unsigned int* __restrict__ featT, const float* __restrict__ coord,
    const float* __restrict__ w_ce, const float* __restrict__ b_ce,
    const float* __restrict__ ln1_g, const float* __restrict__ ln1_b,
    const float* __restrict__ b_o, const float* __restrict__ ln2_g,
    const float* __restrict__ ln2_b, const float* __restrict__ b_m1,
    const float* __restrict__ b_m2, const float* __restrict__ w_head,
    const unsigned short* __restrict__ wprep, float* __restrict__ out)
{
    // Per-wave 12KB: mat0 = Q-staging (aliases A-frag staging "alds"), mat1 = K, mat2 = V.
    __shared__ char smem[4 * 12288];
    const int wid = threadIdx.x >> 6;
    const int lane = threadIdx.x & 63;
    const int g = lane >> 4;
    const int li = lane & 15;
    const int n = ((blockIdx.x << 2) + wid) * 4 + g;
    const int b = n >> 15;
    char* sb = smem + wid * 12288;

    // byte address of a 16B slot: matrix mat, row q = 4*g+nt, li-row (XOR-swizzled)
    auto slot = [&](int mat, int q, int l2) -> char* {
        return sb + mat * 4096 + (((q << 4) | (l2 ^ (q & 7))) << 4);
    };

    // ---- gather + rel-coord embedding ----
    float x[4][4], pred[4];
    const float cy0 = coord[2 * n], cx0 = coord[2 * n + 1];
    float wce0[4], wce1[4], bce[4];
    #pragma unroll
    for (int j = 0; j < 4; ++j) {
        wce0[j] = w_ce[li + 16 * j]; wce1[j] = w_ce[64 + li + 16 * j]; bce[j] = b_ce[li + 16 * j];
    }
    #pragma unroll
    for (int i = 0; i < 4; ++i) {
        float vx = (i < 2) ? -1.0f : 1.0f;
        float vy = (i & 1) ? 1.0f : -1.0f;
        float cy = fminf(fmaxf(cy0 + vx * 0.00390625f + 1e-6f, -1.0f + 1e-6f), 1.0f - 1e-6f);
        float cx = fminf(fmaxf(cx0 + vy * 0.00390625f + 1e-6f, -1.0f + 1e-6f), 1.0f - 1e-6f);
        int iy = min(max((int)rintf((cy + 1.0f) * 128.0f - 0.5f), 0), 255);
        int ix = min(max((int)rintf((cx + 1.0f) * 128.0f - 0.5f), 0), 255);
        int lin = iy * 256 + ix;
        pred[i] = depth[(b << 16) + lin];
        float ysy = -0.99609375f + 0.0078125f * (float)iy;
        float xsx = -0.99609375f + 0.0078125f * (float)ix;
        float rel0 = (cy0 - ysy) * 256.0f;
        float rel1 = (cx0 - xsx) * 256.0f;
        float t0, t1, t2, t3;
        if (USE_T) {
            uint2 w = *(const uint2*)(featT + ((size_t)((b << 16) + lin)) * 32 + 2 * li);
            t0 = __uint_as_float(w.x << 16);
            t1 = __uint_as_float(w.x & 0xffff0000u);
            t2 = __uint_as_float(w.y << 16);
            t3 = __uint_as_float(w.y & 0xffff0000u);
        } else {
            t0 = feat[(((size_t)(b * 64 + li)) << 16) + lin];
            t1 = feat[(((size_t)(b * 64 + li + 16)) << 16) + lin];
            t2 = feat[(((size_t)(b * 64 + li + 32)) << 16) + lin];
            t3 = feat[(((size_t)(b * 64 + li + 48)) << 16) + lin];
        }
        x[i][0] = t0 + rel0 * wce0[0] + rel1 * wce1[0] + bce[0];
        x[i][1] = t1 + rel0 * wce0[1] + rel1 * wce1[1] + bce[1];
        x[i][2] = t2 + rel0 * wce0[2] + rel1 * wce1[2] + bce[2];
        x[i][3] = t3 + rel0 * wce0[3] + rel1 * wce1[3] + bce[3];
    }

    // ---- helpers ----
    auto lnorm = [&](float xv[4][4], float hv[4][4],
                     const float* __restrict__ gp, const float* __restrict__ bp) {
        float gj[4], bj[4];
        #pragma unroll
        for (int j = 0; j < 4; ++j) { gj[j] = gp[li + 16 * j]; bj[j] = bp[li + 16 * j]; }
        #pragma unroll
        for (int i = 0; i < 4; ++i) {
            float s = xv[i][0] + xv[i][1] + xv[i][2] + xv[i][3];
            float ss = xv[i][0] * xv[i][0] + xv[i][1] * xv[i][1]
                     + xv[i][2] * xv[i][2] + xv[i][3] * xv[i][3];
            #pragma unroll
            for (int m = 1; m < 16; m <<= 1) {
                s += __shfl_xor(s, m, 64);
                ss += __shfl_xor(ss, m, 64);
            }
            float mean = s * 0.015625f;
            float var = ss * 0.015625f - mean * mean;
            float rs = rsqrtf(var + 1e-5f);
            #pragma unroll
            for (int j = 0; j < 4; ++j)
                hv[i][j] = (xv[i][j] - mean) * rs * gj[j] + bj[j];
        }
    };

    // D-layout values -> bf16 into A-frag staging (alds = sb mat0 region), swizzled
    auto put16 = [&](const float v[4][4]) {
        #pragma unroll
        for (int i = 0; i < 4; ++i) {
            int r = 4 * g + i;
            int rb = 128 * r + 2 * (li & 7);
            #pragma unroll
            for (int j = 0; j < 4; ++j) {
                unsigned int u;
                asm("v_cvt_pk_bf16_f32 %0, %1, %2" : "=v"(u) : "v"(v[i][j]), "v"(v[i][j]));
                *(unsigned short*)(sb + rb + 16 * ((2 * j + (li >> 3)) ^ (r & 7))) = (unsigned short)u;
            }
        }
        asm volatile("s_waitcnt lgkmcnt(0)" ::: "memory");
    };
    auto get_frags = [&](short8& a0, short8& a1) {
        a0 = *(const short8*)(sb + 128 * li + 16 * (g ^ (li & 7)));
        a1 = *(const short8*)(sb + 128 * li + 16 * ((4 + g) ^ (li & 7)));
    };

    auto gemm = [&](short8 a0, short8 a1, const short8* __restrict__ Wf, f32x4 acc[4]) {
        #pragma unroll
        for (int nt = 0; nt < 4; ++nt) {
            acc[nt] = __builtin_amdgcn_mfma_f32_16x16x32_bf16(a0, Wf[nt * 64 + lane], acc[nt], 0, 0, 0);
            acc[nt] = __builtin_amdgcn_mfma_f32_16x16x32_bf16(a1, Wf[(4 + nt) * 64 + lane], acc[nt], 0, 0, 0);
        }
    };

    const short8* Wq  = (const short8*)(wprep);
    const short8* Wk  = (const short8*)(wprep + 1 * 4096);
    const short8* Wv  = (const short8*)(wprep + 2 * 4096);
    const short8* Wo  = (const short8*)(wprep + 3 * 4096);
    const short8* Wm1 = (const short8*)(wprep + 4 * 4096);
    const short8* Wm2 = (const short8*)(wprep + 5 * 4096);
    const f32x4 z4 = {0.0f, 0.0f, 0.0f, 0.0f};

    // ---- LN1 + QKV ----
    float h[4][4];
    lnorm(x, h, ln1_g, ln1_b);
    short8 a0, a1;
    put16(h);
    get_frags(a0, a1);
    f32x4 qa[4], ka[4], va[4];
    #pragma unroll
    for (int t = 0; t < 4; ++t) { qa[t] = z4; ka[t] = z4; va[t] = z4; }
    gemm(a0, a1, Wq, qa);
    gemm(a0, a1, Wk, ka);
    gemm(a0, a1, Wv, va);

    // ---- attention: stage Q,K,V (f32, pos-contig 16B rows, XOR-swizzled) ----
    // qa[nt] is float4 over pos i -> exactly one 16B slot.
    #pragma unroll
    for (int nt = 0; nt < 4; ++nt) {
        *(f32x4*)slot(0, 4 * g + nt, li) = qa[nt];
        *(f32x4*)slot(1, 4 * g + nt, li) = ka[nt];
        *(f32x4*)slot(2, 4 * g + nt, li) = va[nt];
    }
    asm volatile("s_waitcnt lgkmcnt(0)" ::: "memory");

    // unit lane: token gp (=g), head hp, row-half
    const int hp = (lane & 15) >> 1;
    const int half = lane & 1;
    const int qrow = 4 * g + (hp >> 1);          // staging row for (g, nt=hp>>1)
    const int lb = 8 * (hp & 1);                 // li-base of this head's 8 d-rows
    float4 kk[8]; float2 qq[8];
    #pragma unroll
    for (int d = 0; d < 8; ++d) {
        kk[d] = *(const float4*)slot(1, qrow, lb + d);
        qq[d] = *(const float2*)(slot(0, qrow, lb + d) + 8 * half);
    }
    float S[2][4];
    #pragma unroll
    for (int t = 0; t < 2; ++t)
        #pragma unroll
        for (int s = 0; s < 4; ++s) {
            float acc = qq[0][t] * kk[0][s];
            #pragma unroll
            for (int d = 1; d < 8; ++d) acc += qq[d][t] * kk[d][s];
            S[t][s] = acc * 0.35355339059327378f;
        }
    float P[2][4];
    #pragma unroll
    for (int t = 0; t < 2; ++t) {
        float m = fmaxf(fmaxf(S[t][0], S[t][1]), fmaxf(S[t][2], S[t][3]));
        float e0 = __expf(S[t][0] - m), e1 = __expf(S[t][1] - m);
        float e2 = __expf(S[t][2] - m), e3 = __expf(S[t][3] - m);
        float inv = 1.0f / (e0 + e1 + e2 + e3);
        P[t][0] = e0 * inv; P[t][1] = e1 * inv; P[t][2] = e2 * inv; P[t][3] = e3 * inv;
    }
    float4 vv[8];
    #pragma unroll
    for (int d = 0; d < 8; ++d) vv[d] = *(const float4*)slot(2, qrow, lb + d);
    // O[t][d] = sum_s P[t][s]*V[s][d]; write straight into A-frag staging as bf16
    #pragma unroll
    for (int t = 0; t < 2; ++t) {
        float O[8];
        #pragma unroll
        for (int d = 0; d < 8; ++d)
            O[d] = P[t][0] * vv[d].x + P[t][1] * vv[d].y + P[t][2] * vv[d].z + P[t][3] * vv[d].w;
        unsigned int u0, u1, u2, u3;
        asm("v_cvt_pk_bf16_f32 %0, %1, %2" : "=v"(u0) : "v"(O[0]), "v"(O[1]));
        asm("v_cvt_pk_bf16_f32 %0, %1, %2" : "=v"(u1) : "v"(O[2]), "v"(O[3]));
        asm("v_cvt_pk_bf16_f32 %0, %1, %2" : "=v"(u2) : "v"(O[4]), "v"(O[5]));
        asm("v_cvt_pk_bf16_f32 %0, %1, %2" : "=v"(u3) : "v"(O[6]), "v"(O[7]));
        int row = 4 * g + 2 * half + t;
        *(uint4*)(sb + 128 * row + 16 * (hp ^ (row & 7))) = make_uint4(u0, u1, u2, u3);
    }
    asm volatile("s_waitcnt lgkmcnt(0)" ::: "memory");

    // ---- o @ w_o + b_o + residual ----
    get_frags(a0, a1);
    f32x4 oa[4];
    #pragma unroll
    for (int t = 0; t < 4; ++t) oa[t] = z4;
    gemm(a0, a1, Wo, oa);
    {
        float bo[4];
        #pragma unroll
        for (int j = 0; j < 4; ++j) bo[j] = b_o[li + 16 * j];
        #pragma unroll
        for (int i = 0; i < 4; ++i)
            #pragma unroll
            for (int j = 0; j < 4; ++j) x[i][j] += oa[j][i] + bo[j];
    }

    // ---- LN2 + MLP ----
    float h2[4][4];
    lnorm(x, h2, ln2_g, ln2_b);
    put16(h2);
    get_frags(a0, a1);
    f32x4 ma[4];
    #pragma unroll
    for (int t = 0; t < 4; ++t) ma[t] = z4;
    gemm(a0, a1, Wm1, ma);
    float g1[4][4];
    {
        float bm[4];
        #pragma unroll
        for (int j = 0; j < 4; ++j) bm[j] = b_m1[li + 16 * j];
        #pragma unroll
        for (int i = 0; i < 4; ++i)
            #pragma unroll
            for (int j = 0; j < 4; ++j) g1[i][j] = gelu_tanh(ma[j][i] + bm[j]);
    }
    put16(g1);
    get_frags(a0, a1);
    f32x4 m2a[4];
    #pragma unroll
    for (int t = 0; t < 4; ++t) m2a[t] = z4;
    gemm(a0, a1, Wm2, m2a);
    {
        float bm[4];
        #pragma unroll
        for (int j = 0; j < 4; ++j) bm[j] = b_m2[li + 16 * j];
        #pragma unroll
        for (int i = 0; i < 4; ++i)
            #pragma unroll
            for (int j = 0; j < 4; ++j) x[i][j] += m2a[j][i] + bm[j];
    }

    // ---- head softmax over 4 positions; weighted depth blend ----
    float wh[4];
    #pragma unroll
    for (int j = 0; j < 4; ++j) wh[j] = w_head[li + 16 * j];
    float lg[4];
    #pragma unroll
    for (int i = 0; i < 4; ++i) {
        float s = x[i][0] * wh[0] + x[i][1] * wh[1] + x[i][2] * wh[2] + x[i][3] * wh[3];
        #pragma unroll
        for (int m = 1; m < 16; m <<= 1) s += __shfl_xor(s, m, 64);
        lg[i] = s;
    }
    float m = fmaxf(fmaxf(lg[0], lg[1]), fmaxf(lg[2], lg[3]));
    float e0 = __expf(lg[0] - m), e1 = __expf(lg[1] - m);
    float e2 = __expf(lg[2] - m), e3 = __expf(lg[3] - m);
    float res = (pred[0] * e0 + pred[1] * e1 + pred[2] * e2 + pred[3] * e3)
              / (e0 + e1 + e2 + e3);
    if (li == 0) out[n] = res;
}

extern "C" void kernel_launch(void* const* d_in, const int* in_sizes, int n_in,
                              void* d_out, int out_size, void* d_ws, size_t ws_size,
                              hipStream_t stream) {
    const float* depth  = (const float*)d_in[0];
    const float* feat   = (const float*)d_in[1];
    const float* coord  = (const float*)d_in[2];
    const float* w_ce   = (const float*)d_in[3];
    const float* b_ce   = (const float*)d_in[4];
    const float* ln1_g  = (const float*)d_in[5];
    const float* ln1_b  = (const float*)d_in[6];
    const float* w_q    = (const float*)d_in[7];
    const float* w_k    = (const float*)d_in[8];
    const float* w_v    = (const float*)d_in[9];
    const float* w_o    = (const float*)d_in[10];
    const float* b_o    = (const float*)d_in[11];
    const float* ln2_g  = (const float*)d_in[12];
    const float* ln2_b  = (const float*)d_in[13];
    const float* w_m1   = (const float*)d_in[14];
    const float* b_m1   = (const float*)d_in[15];
    const float* w_m2   = (const float*)d_in[16];
    const float* b_m2   = (const float*)d_in[17];
    const float* w_head = (const float*)d_in[18];
    float* outp = (float*)d_out;

    unsigned short* wprep = (unsigned short*)d_ws;
    const size_t FEATT_OFF = 65536;                           // wprep uses 49152 B
    const size_t featT_bytes = (size_t)NB * NHW * 64 * 2;     // bf16
    unsigned int* featT = (unsigned int*)((char*)d_ws + FEATT_OFF);
    bool use_t = (d_ws != nullptr) && (ws_size >= FEATT_OFF + featT_bytes);

    wprep_kernel<<<48, 64, 0, stream>>>(w_q, w_k, w_v, w_o, w_m1, w_m2, wprep);
    if (use_t) {
        feat_transpose_kernel<<<NB * (NHW / 64), 256, 0, stream>>>(feat, featT);
        token_kernel<true><<<NTOK / 16, 256, 0, stream>>>(
            depth, feat, featT, coord, w_ce, b_ce, ln1_g, ln1_b,
            b_o, ln2_g, ln2_b, b_m1, b_m2, w_head, wprep, outp);
    } else {
        token_kernel<false><<<NTOK / 16, 256, 0, stream>>>(
            depth, feat, featT, coord, w_ce, b_ce, ln1_g, ln1_b,
            b_o, ln2_g, ln2_b, b_m1, b_m2, w_head, wprep, outp);
    }
}